// Round 1
// baseline (3859.504 us; speedup 1.0000x reference)
//
#include <hip/hip_runtime.h>
#include <math.h>

#define NN 64
#define DD 512
#define OUTC 300
#define KN 63            // N-1 neighbors
#define NPAIR 16384      // B*2
#define ROWS 32          // pairs per gemv block (16 batch elems)

// ---------------------------------------------------------------------------
// Kernel 1: per-pair attention + context via online softmax (single HBM pass).
// One wave (64 lanes) per pair; lane holds d-elements {4i..4i+3, 256+4i..+3}.
// ---------------------------------------------------------------------------
__global__ __launch_bounds__(256) void attn_ctx_kernel(
    const float* __restrict__ x, const float* __restrict__ v,
    float* __restrict__ ctx)
{
    const int tid  = threadIdx.x;
    const int lane = tid & 63;
    const int w    = tid >> 6;
    const int p    = blockIdx.x * 4 + w;          // pair index = b*2 + s
    const float* base = x + (size_t)p * (NN * DD);

    // node fragment (k = 0 row)
    const float4* nodev = (const float4*)base;
    const float4 na = nodev[lane];
    const float4 nb = nodev[64 + lane];

    float m = -3.0e38f, l = 0.0f;
    float cax = 0.f, cay = 0.f, caz = 0.f, caw = 0.f;
    float cbx = 0.f, cby = 0.f, cbz = 0.f, cbw = 0.f;

    for (int k = 0; k < KN; ++k) {
        const float4* nk = (const float4*)(base + (size_t)(k + 1) * DD);
        const float4 qa = nk[lane];
        const float4 qb = nk[64 + lane];
        float s = qa.x*na.x + qa.y*na.y + qa.z*na.z + qa.w*na.w
                + qb.x*nb.x + qb.y*nb.y + qb.z*nb.z + qb.w*nb.w;
        #pragma unroll
        for (int off = 32; off > 0; off >>= 1)
            s += __shfl_xor(s, off, 64);
        // mask: att==0 -> att - 9999  (reference: att + ((att!=0)-1)*9999)
        if (s == 0.0f) s -= 9999.0f;
        const float vk = v[k];                    // wave-uniform scalar load
        const float nm = fmaxf(m, s);
        const float ef = __expf(m - nm);          // rescale old state
        const float es = __expf(s - nm);
        l = l * ef + es;
        const float wg = vk * es;
        cax = cax*ef + wg*qa.x;  cay = cay*ef + wg*qa.y;
        caz = caz*ef + wg*qa.z;  caw = caw*ef + wg*qa.w;
        cbx = cbx*ef + wg*qb.x;  cby = cby*ef + wg*qb.y;
        cbz = cbz*ef + wg*qb.z;  cbw = cbw*ef + wg*qb.w;
        m = nm;
    }
    const float invl = 1.0f / l;
    float4 oa = make_float4(cax*invl, cay*invl, caz*invl, caw*invl);
    float4 ob = make_float4(cbx*invl, cby*invl, cbz*invl, cbw*invl);
    float4* op = (float4*)(ctx + (size_t)p * DD);
    op[lane]      = oa;
    op[64 + lane] = ob;
}

// ---------------------------------------------------------------------------
// Kernel 2: batched GEMV r = [node, context] @ W^T + b, fused cosine epilogue.
// Block = 320 threads; thread t <-> output column t (t<300); 32 rows/block
// kept as per-thread accumulators; cat values are wave-uniform scalar loads.
// ---------------------------------------------------------------------------
__global__ __launch_bounds__(320) void gemv_cos_kernel(
    const float* __restrict__ x, const float* __restrict__ ctx,
    const float* __restrict__ W, const float* __restrict__ bias,
    float* __restrict__ out)
{
    const int t     = threadIdx.x;
    const int tc    = (t < OUTC) ? t : (OUTC - 1);   // clamp for safe loads
    const bool valid = (t < OUTC);
    const int p0    = blockIdx.x * ROWS;             // first pair of block

    float acc[ROWS];
    const float bv = bias[tc];
    #pragma unroll
    for (int r = 0; r < ROWS; ++r) acc[r] = bv;

    const float* wrow = W + (size_t)tc * (2 * DD);

    // --- node half: i in [0, 512) ---
    for (int i = 0; i < DD; i += 4) {
        const float4 w4 = *(const float4*)(wrow + i);
        #pragma unroll
        for (int r = 0; r < ROWS; ++r) {
            const float4 a4 = *(const float4*)(x + (size_t)(p0 + r) * (NN * DD) + i);
            acc[r] += a4.x*w4.x + a4.y*w4.y + a4.z*w4.z + a4.w*w4.w;
        }
    }
    // --- context half: i in [512, 1024) ---
    for (int i = 0; i < DD; i += 4) {
        const float4 w4 = *(const float4*)(wrow + DD + i);
        #pragma unroll
        for (int r = 0; r < ROWS; ++r) {
            const float4 a4 = *(const float4*)(ctx + (size_t)(p0 + r) * DD + i);
            acc[r] += a4.x*w4.x + a4.y*w4.y + a4.z*w4.z + a4.w*w4.w;
        }
    }

    // --- fused cosine: per batch elem bi, rows (2bi, 2bi+1) ---
    __shared__ float red[5][ROWS / 2][3];
    const int lane = t & 63;
    const int w    = t >> 6;
    #pragma unroll
    for (int bi = 0; bi < ROWS / 2; ++bi) {
        const float a0 = acc[2 * bi], a1 = acc[2 * bi + 1];
        float pd = valid ? a0 * a1 : 0.f;
        float q0 = valid ? a0 * a0 : 0.f;
        float q1 = valid ? a1 * a1 : 0.f;
        #pragma unroll
        for (int off = 32; off > 0; off >>= 1) {
            pd += __shfl_xor(pd, off, 64);
            q0 += __shfl_xor(q0, off, 64);
            q1 += __shfl_xor(q1, off, 64);
        }
        if (lane == 0) {
            red[w][bi][0] = pd; red[w][bi][1] = q0; red[w][bi][2] = q1;
        }
    }
    __syncthreads();
    if (t < ROWS / 2) {
        float pd = 0.f, q0 = 0.f, q1 = 0.f;
        #pragma unroll
        for (int w2 = 0; w2 < 5; ++w2) {
            pd += red[w2][t][0]; q0 += red[w2][t][1]; q1 += red[w2][t][2];
        }
        const float n0 = fmaxf(sqrtf(q0), 1e-8f);
        const float n1 = fmaxf(sqrtf(q1), 1e-8f);
        out[blockIdx.x * (ROWS / 2) + t] = pd / (n0 * n1);
    }
}

extern "C" void kernel_launch(void* const* d_in, const int* in_sizes, int n_in,
                              void* d_out, int out_size, void* d_ws, size_t ws_size,
                              hipStream_t stream) {
    const float* x    = (const float*)d_in[0];   // (8192, 2, 64, 512) fp32
    const float* v    = (const float*)d_in[1];   // (63,)
    const float* W    = (const float*)d_in[2];   // (300, 1024)
    const float* bias = (const float*)d_in[3];   // (300,)
    float* out = (float*)d_out;                  // (8192,)
    float* ctx = (float*)d_ws;                   // (16384, 512) fp32 = 32 MiB

    attn_ctx_kernel<<<NPAIR / 4, 256, 0, stream>>>(x, v, ctx);
    gemv_cos_kernel<<<NPAIR / ROWS, 320, 0, stream>>>(x, ctx, W, bias, out);
}